// Round 1
// baseline (776.924 us; speedup 1.0000x reference)
//
#include <hip/hip_runtime.h>
#include <math.h>

#define B_ 64
#define T_ 1024
#define D_ 256
#define U_ 256

typedef _Float16 h2_t __attribute__((ext_vector_type(2)));
typedef _Float16 h8_t __attribute__((ext_vector_type(8)));

// ---------------------------------------------------------------------------
// Kernel 1: proj = inputs @ W_xh + b_h, written into d_out (reused as xW buf).
// (unchanged — isolate the rnn_scan restructure this round)
// ---------------------------------------------------------------------------
#define BM 64
#define BN 64
#define BK 16

__global__ __launch_bounds__(256, 2)
void proj_gemm(const float* __restrict__ A,      // [M, D_] inputs
               const float* __restrict__ Bm,     // [D_, U_] W_xh
               const float* __restrict__ bias,   // [U_]
               float* __restrict__ C) {          // [M, U_] out
    __shared__ float As[BK][BM];   // transposed A tile: As[k][m]
    __shared__ float Bs[BK][BN];

    const int m0 = blockIdx.x * BM;
    const int n0 = blockIdx.y * BN;
    const int tid = (int)threadIdx.x;
    const int tx = tid & 15;
    const int ty = tid >> 4;

    const int ar  = tid >> 2;
    const int akq = tid & 3;
    const int bk  = tid >> 4;
    const int bnq = tid & 15;

    float acc[4][4] = {};

    for (int k0 = 0; k0 < D_; k0 += BK) {
        float4 av = *(const float4*)&A[(size_t)(m0 + ar) * D_ + k0 + akq * 4];
        float4 bv = *(const float4*)&Bm[(size_t)(k0 + bk) * U_ + n0 + bnq * 4];
        __syncthreads();
        As[akq * 4 + 0][ar] = av.x;
        As[akq * 4 + 1][ar] = av.y;
        As[akq * 4 + 2][ar] = av.z;
        As[akq * 4 + 3][ar] = av.w;
        *(float4*)&Bs[bk][bnq * 4] = bv;
        __syncthreads();
        #pragma unroll
        for (int kk = 0; kk < BK; ++kk) {
            float4 a = *(const float4*)&As[kk][ty * 4];
            float4 b = *(const float4*)&Bs[kk][tx * 4];
            acc[0][0] = fmaf(a.x, b.x, acc[0][0]);
            acc[0][1] = fmaf(a.x, b.y, acc[0][1]);
            acc[0][2] = fmaf(a.x, b.z, acc[0][2]);
            acc[0][3] = fmaf(a.x, b.w, acc[0][3]);
            acc[1][0] = fmaf(a.y, b.x, acc[1][0]);
            acc[1][1] = fmaf(a.y, b.y, acc[1][1]);
            acc[1][2] = fmaf(a.y, b.z, acc[1][2]);
            acc[1][3] = fmaf(a.y, b.w, acc[1][3]);
            acc[2][0] = fmaf(a.z, b.x, acc[2][0]);
            acc[2][1] = fmaf(a.z, b.y, acc[2][1]);
            acc[2][2] = fmaf(a.z, b.z, acc[2][2]);
            acc[2][3] = fmaf(a.z, b.w, acc[2][3]);
            acc[3][0] = fmaf(a.w, b.x, acc[3][0]);
            acc[3][1] = fmaf(a.w, b.y, acc[3][1]);
            acc[3][2] = fmaf(a.w, b.z, acc[3][2]);
            acc[3][3] = fmaf(a.w, b.w, acc[3][3]);
        }
    }

    const float4 bb = *(const float4*)&bias[n0 + tx * 4];
    #pragma unroll
    for (int i = 0; i < 4; ++i) {
        const int row = m0 + ty * 4 + i;
        float4 o;
        o.x = acc[i][0] + bb.x;
        o.y = acc[i][1] + bb.y;
        o.z = acc[i][2] + bb.z;
        o.w = acc[i][3] + bb.w;
        *(float4*)&C[(size_t)row * U_ + n0 + tx * 4] = o;
    }
}

// ---------------------------------------------------------------------------
// fast tanh (validated R3: absmax unchanged vs tanhf)
// ---------------------------------------------------------------------------
__device__ __forceinline__ float fast_tanh(float x) {
    float a = fminf(fabsf(x) * 2.0f, 20.0f);
    float e = __expf(a);
    float t = 1.0f - 2.0f * __builtin_amdgcn_rcpf(e + 1.0f);
    return copysignf(t, x);
}

// ---------------------------------------------------------------------------
// quad (lanes {4m..4m+3}) butterfly sum via DPP quad_perm — pure VALU,
// no LDS, no waitcnt. 0xB1 = perm(1,0,3,2) (xor1), 0x4E = perm(2,3,0,1) (xor2).
// ---------------------------------------------------------------------------
__device__ __forceinline__ float quad_reduce(float x) {
    x += __int_as_float(__builtin_amdgcn_update_dpp(
            0, __float_as_int(x), 0xB1, 0xF, 0xF, true));
    x += __int_as_float(__builtin_amdgcn_update_dpp(
            0, __float_as_int(x), 0x4E, 0xF, 0xF, true));
    return x;
}

// ---------------------------------------------------------------------------
// Kernel 2: recurrence. One block/batch, 512 threads = 8 waves (2/SIMD).
//
// RESTRUCTURE vs previous version (which was 2 barriers/step + a serial
// finalize on 2 waves + an LDS round trip for the cross-wave k-reduction;
// measured 1337 cyc/step vs ~350 cyc of issue => ~1000 cyc stall):
//   * wave kg owns u-range [32kg,32kg+32) over ALL k=256. Within the wave,
//     lane = (u-pair up=lane>>2, k-quarter q=lane&3): 64 k x 2 u per lane
//     -> same 64 fdot2/lane and same 64-VGPR f16 W slice as before.
//   * k-reduction is now wave-internal: DPP quad reduce (2 v_add_f32 with
//     quad_perm) instead of part[] LDS write + barrier + read.
//   * finalize (xw add, tanh, writes) runs on all 8 waves for their own u.
//   * h state double-buffered (hlds[2]) -> ONE __syncthreads per step.
//   * hlds padded 4x36 h2 (144B stride, 16B aligned): the 4 k-quarter
//     multicast groups land on disjoint bank quads -> conflict-free
//     ds_read_b128 with compile-time wreg indices (no scratch).
// ---------------------------------------------------------------------------
#define CH_  16
#define NT2_ 512

__global__ __launch_bounds__(NT2_) __attribute__((amdgpu_waves_per_eu(2, 2)))
void rnn_scan(const float* __restrict__ W_hh,   // [U_, U_]
              float* __restrict__ out) {        // [B_, T_, U_]: xW in, h out
    const int b    = (int)blockIdx.x;
    const int tid  = (int)threadIdx.x;
    const int kg   = tid >> 6;        // wave 0..7: owns u in [32kg, 32kg+32)
    const int lane = tid & 63;
    const int q    = lane & 3;        // k-quarter: k in [64q, 64q+64)
    const int up   = lane >> 2;       // u-pair within wave: 0..15
    const int u0   = kg * 32 + 2 * up;

    __shared__ float buf[2][CH_][U_];            // xw in / h out, double-buffered
    __shared__ __align__(16) h2_t hlds[2][148];  // h f16-pairs, 4x36 padded, dbuf

    // W_hh slice -> f16 pair registers:
    // wreg[kk][c] = (W[64q+2kk][u0+c], W[64q+2kk+1][u0+c]),  kk = 0..31
    h2_t wreg[32][2];
    #pragma unroll
    for (int kk = 0; kk < 32; ++kk) {
        const int r0 = 64 * q + 2 * kk;
        const float2 wa = *(const float2*)&W_hh[(size_t)r0 * U_ + u0];
        const float2 wb = *(const float2*)&W_hh[(size_t)(r0 + 1) * U_ + u0];
        wreg[kk][0] = h2_t{(_Float16)wa.x, (_Float16)wb.x};
        wreg[kk][1] = h2_t{(_Float16)wa.y, (_Float16)wb.y};
    }

    if (tid < 144) hlds[0][tid] = h2_t{(_Float16)0.f, (_Float16)0.f};

    float* gbase = out + (size_t)b * T_ * U_;

    // load chunk 0 -> buf[0]  (flat 4096 floats, 8 per thread, coalesced)
    {
        float4 v0 = *(const float4*)&gbase[8 * tid];
        float4 v1 = *(const float4*)&gbase[8 * tid + 4];
        float* bf = &buf[0][0][0];
        *(float4*)&bf[8 * tid]     = v0;
        *(float4*)&bf[8 * tid + 4] = v1;
    }
    __syncthreads();

    // per-lane LDS index constants (padded layout: quarter qd at h2 ofs 36*qd)
    const int hread  = q * 36;                   // read base (h2 idx) for my quarter
    const int iown   = 16 * kg + up;             // owned h2-pair index 0..127
    const int hwrite = (iown >> 5) * 36 + (iown & 31);

    int cur = 0;
    int hp  = 0;                                 // h parity: read hlds[hp], write hlds[hp^1]
    for (int c = 0; c < T_ / CH_; ++c) {
        // prefetch chunk c+1 into buf[1-cur]; same-thread same-address as the
        // dump below -> no cross-thread hazard; step barriers order visibility.
        if (c + 1 < T_ / CH_) {
            const float* gsrc = gbase + (size_t)(c + 1) * CH_ * U_;
            float4 v0 = *(const float4*)&gsrc[8 * tid];
            float4 v1 = *(const float4*)&gsrc[8 * tid + 4];
            float* bf = &buf[1 - cur][0][0];
            *(float4*)&bf[8 * tid]     = v0;
            *(float4*)&bf[8 * tid + 4] = v1;
        }

        for (int j = 0; j < CH_; ++j) {
            const float2 xw = *(const float2*)&buf[cur][j][u0];  // 4-lane broadcast
            const h2_t* hb = &hlds[hp][hread];
            float ax0 = 0.f, ay0 = 0.f, ax1 = 0.f, ay1 = 0.f;
            #pragma unroll
            for (int cc = 0; cc < 8; ++cc) {
                const h8_t hv = *(const h8_t*)&hb[4 * cc];   // b128, conflict-free
                #pragma unroll
                for (int jj = 0; jj < 4; ++jj) {
                    const h2_t hpair = h2_t{hv[2 * jj], hv[2 * jj + 1]};
                    const int kk = 4 * cc + jj;              // compile-time
                    if (cc & 1) {
                        ax1 = __builtin_amdgcn_fdot2(hpair, wreg[kk][0], ax1, false);
                        ay1 = __builtin_amdgcn_fdot2(hpair, wreg[kk][1], ay1, false);
                    } else {
                        ax0 = __builtin_amdgcn_fdot2(hpair, wreg[kk][0], ax0, false);
                        ay0 = __builtin_amdgcn_fdot2(hpair, wreg[kk][1], ay0, false);
                    }
                }
            }
            // cross-k-quarter reduce: in-register, lanes {4up..4up+3}
            const float sx = quad_reduce(ax0 + ax1) + xw.x;
            const float sy = quad_reduce(ay0 + ay1) + xw.y;
            const float hx = fast_tanh(sx);
            const float hy = fast_tanh(sy);
            if (q == 0) {
                *(float2*)&buf[cur][j][u0] = make_float2(hx, hy);        // h out
                hlds[hp ^ 1][hwrite] = h2_t{(_Float16)hx, (_Float16)hy}; // next h
            }
            __syncthreads();            // ONE barrier/step: hlds[hp^1] now ready
            hp ^= 1;
        }

        // ---- dump chunk (now holding h) -> global, coalesced
        {
            float* gdst = gbase + (size_t)c * CH_ * U_;
            const float* bf = &buf[cur][0][0];
            float4 v0 = *(const float4*)&bf[8 * tid];
            float4 v1 = *(const float4*)&bf[8 * tid + 4];
            *(float4*)&gdst[8 * tid]     = v0;
            *(float4*)&gdst[8 * tid + 4] = v1;
        }
        cur ^= 1;
    }
}

// ---------------------------------------------------------------------------
extern "C" void kernel_launch(void* const* d_in, const int* in_sizes, int n_in,
                              void* d_out, int out_size, void* d_ws, size_t ws_size,
                              hipStream_t stream) {
    const float* inputs = (const float*)d_in[0];   // [B, T, D]
    const float* W_xh   = (const float*)d_in[1];   // [D, U]
    const float* W_hh   = (const float*)d_in[2];   // [U, U]
    const float* b_h    = (const float*)d_in[3];   // [U]
    float* out = (float*)d_out;                    // [B, T, U]

    const int M = B_ * T_;                         // 65536
    dim3 g1(M / BM, U_ / BN);                      // (1024, 4)
    proj_gemm<<<g1, 256, 0, stream>>>(inputs, W_xh, b_h, out);
    rnn_scan<<<B_, NT2_, 0, stream>>>(W_hh, out);
}